// Round 4
// baseline (371.717 us; speedup 1.0000x reference)
//
#include <hip/hip_runtime.h>
#include <stdint.h>
#include <math.h>

#define BDIM   2
#define CDIM   16
#define INS    64
#define OUTS   20
#define NPTS   8000          // 20^3
#define TOTN   (BDIM*NPTS)   // 16000
#define NCHUNK 8
#define MCHUNK 1000

// ---------------- ws layout (bytes, all 8B-aligned) ----------------
// sfeat  : 0        +2,048,000   (B,N,C) f64
// tfeat  : 2048000  +2,048,000   (B,N,C) f64
// t2     : 4096000  +128,000     (B,N)   f64
// pscore : 4224000  +1,024,000   (B,chunk,N) f64
// pidx   : 5248000  +512,000     (B,chunk,N) i32
// lpart  : 5760000  +504         63 block partials f64
// total ~5.76 MB

// Trilinear resize 64^3 -> 20^3 matching jax.image.resize(method='trilinear',
// antialias=True). All math in f64. (Unchanged — known exact.)
__global__ void k_resize(const float* __restrict__ src, const float* __restrict__ tgt,
                         double* __restrict__ sfeat, double* __restrict__ tfeat) {
    __shared__ double wts[OUTS][8];
    __shared__ int    st[OUTS];
    __shared__ int    cnt[OUTS];
    int tid = threadIdx.x;
    if (tid < OUTS) {
        double sample = (tid + 0.5) * 3.2 - 0.5;
        int lo = (int)ceil(sample - 3.2);
        int hi = (int)floor(sample + 3.2);
        if (lo < 0) lo = 0;
        if (hi > INS - 1) hi = INS - 1;
        int c = hi - lo + 1;           // <= 7
        double w[8];
        double sum = 0.0;
        for (int k = 0; k < 8; ++k) {
            double ww = 0.0;
            if (k < c) {
                double x = fabs(sample - (double)(lo + k)) * (1.0 / 3.2);
                ww = (x < 1.0) ? (1.0 - x) : 0.0;
            }
            w[k] = ww; sum += ww;
        }
        for (int k = 0; k < 8; ++k) wts[tid][k] = w[k] / sum;
        st[tid] = lo; cnt[tid] = c;
    }
    __syncthreads();

    int gid = blockIdx.x * blockDim.x + tid;     // [sel][b][c][od][oh][ow], 512000 total
    int ow = gid % OUTS; int r = gid / OUTS;
    int oh = r % OUTS;  r /= OUTS;
    int od = r % OUTS;  r /= OUTS;
    int c  = r % CDIM;  r /= CDIM;
    int b  = r % BDIM;  r /= BDIM;
    int sel = r;                                  // 0=src, 1=tgt

    const float* in   = sel ? tgt : src;
    double*      outf = sel ? tfeat : sfeat;

    const float* base = in + (((size_t)(b * CDIM + c)) << 18);   // * 64*64*64
    int sd = st[od], sh = st[oh], sw = st[ow];
    int cd = cnt[od], ch = cnt[oh], cw = cnt[ow];
    double wwv[8];
    for (int k = 0; k < 8; ++k) wwv[k] = wts[ow][k];

    double acc = 0.0;
    for (int id = 0; id < cd; ++id) {
        double wd = wts[od][id];
        const float* pd = base + ((size_t)(sd + id) << 12);
        for (int ih = 0; ih < ch; ++ih) {
            double wdh = wd * wts[oh][ih];
            const float* row = pd + ((sh + ih) << 6) + sw;
            for (int iw = 0; iw < cw; ++iw)
                acc = fma(wdh * wwv[iw], (double)row[iw], acc);
        }
    }
    int n = (od * OUTS + oh) * OUTS + ow;
    outf[((size_t)(b * NPTS + n)) * CDIM + c] = acc;
}

__global__ void k_t2(const double* __restrict__ tfeat, double* __restrict__ t2) {
    int i = blockIdx.x * blockDim.x + threadIdx.x;
    if (i >= TOTN) return;
    const double* p = tfeat + (size_t)i * CDIM;
    double a = 0, b = 0, c = 0, d = 0;
#pragma unroll
    for (int k = 0; k < 4; ++k) {
        a = fma(p[4*k+0], p[4*k+0], a);
        b = fma(p[4*k+1], p[4*k+1], b);
        c = fma(p[4*k+2], p[4*k+2], c);
        d = fma(p[4*k+3], p[4*k+3], d);
    }
    t2[i] = (a + b) + (c + d);
}

// Exact f64 argmin, register-tiled T=2 n/thread (s-tile 64 VGPR -> fully
// resident under the 128-VGPR / 4-waves-per-EU budget). Block = 256 thr
// (4 waves) covers 128 n's x one m-chunk of 1000; waves stride-interleave m
// (m = chunk*1000 + wp + 4i) for L1 line reuse. Scores arithmetic-identical
// to previous rounds (bitwise-exact argmin).
__global__ __launch_bounds__(256, 4) void k_argmin(const double* __restrict__ sfeat,
                                                   const double* __restrict__ tfeat,
                                                   const double* __restrict__ t2,
                                                   double* __restrict__ pscore,
                                                   int* __restrict__ pidx) {
    int b     = blockIdx.z;
    int chunk = blockIdx.y;
    int nbase = blockIdx.x << 7;                 // *128
    int lane  = threadIdx.x & 63;
    int wp    = threadIdx.x >> 6;                // 0..3

    double s[2][16];
#pragma unroll
    for (int j = 0; j < 2; ++j) {
        int n = nbase + (j << 6) + lane;
        if (n > NPTS - 1) n = NPTS - 1;          // pad clamp (last tile)
        const double* sr = sfeat + ((size_t)(b * NPTS + n)) * CDIM;
#pragma unroll
        for (int k = 0; k < CDIM; ++k) s[j][k] = sr[k];
    }

    const double* tb  = tfeat + (size_t)b * NPTS * CDIM;
    const double* t2b = t2 + b * NPTS;

    double best[2] = {1e300, 1e300};
    int    bm[2]   = {0, 0};
    int mstart = chunk * MCHUNK + wp;

#pragma unroll 2
    for (int i = 0; i < MCHUNK / 4; ++i) {
        int m = mstart + (i << 2);
        const double* tr = tb + (size_t)m * CDIM;
        double t[16];
#pragma unroll
        for (int k = 0; k < CDIM; ++k) t[k] = tr[k];
        double t2v = t2b[m];
#pragma unroll
        for (int j = 0; j < 2; ++j) {
            double d0 = 0, d1 = 0, d2 = 0, d3 = 0;
#pragma unroll
            for (int k = 0; k < 4; ++k) {
                d0 = fma(s[j][4*k+0], t[4*k+0], d0);
                d1 = fma(s[j][4*k+1], t[4*k+1], d1);
                d2 = fma(s[j][4*k+2], t[4*k+2], d2);
                d3 = fma(s[j][4*k+3], t[4*k+3], d3);
            }
            double dot   = (d0 + d1) + (d2 + d3);
            double score = fma(-2.0, dot, t2v);
            if (score < best[j]) { best[j] = score; bm[j] = m; }  // m ascending per thread
        }
    }

    // merge 4 waves' candidates for the same 128 n's (exact lexicographic)
    __shared__ double sc[512];
    __shared__ int    sm[512];
#pragma unroll
    for (int j = 0; j < 2; ++j) {
        sc[wp * 128 + (j << 6) + lane] = best[j];
        sm[wp * 128 + (j << 6) + lane] = bm[j];
    }
    __syncthreads();

    int tid = threadIdx.x;
    if (tid < 128) {
        double b0 = sc[tid];
        int    i0 = sm[tid];
#pragma unroll
        for (int p = 1; p < 4; ++p) {
            double bp = sc[p * 128 + tid];
            int    ip = sm[p * 128 + tid];
            if (bp < b0 || (bp == b0 && ip < i0)) { b0 = bp; i0 = ip; }
        }
        int n = nbase + tid;
        if (n < NPTS) {
            size_t o = ((size_t)(b * NCHUNK + chunk)) * NPTS + n;
            pscore[o] = b0;
            pidx[o]   = i0;
        }
    }
}

// Merge chunks (ascending, strict < => earliest m wins ties) + partial loss.
__global__ void k_mergeloss(const double* __restrict__ pscore,
                            const int* __restrict__ pidx,
                            const float* __restrict__ expd,
                            double* __restrict__ lpart) {
    int gid = blockIdx.x * 256 + threadIdx.x;    // 63*256 = 16128 >= 16000
    double sum = 0.0;
    if (gid < TOTN) {
        int b  = gid / NPTS;
        int nn = gid % NPTS;
        size_t o = ((size_t)(b * NCHUNK)) * NPTS + nn;
        double b0 = pscore[o];
        int    i0 = pidx[o];
#pragma unroll
        for (int c = 1; c < NCHUNK; ++c) {
            double bp = pscore[o + (size_t)c * NPTS];
            int    ip = pidx[o + (size_t)c * NPTS];
            if (bp < b0) { b0 = bp; i0 = ip; }   // idx ascends with chunk
        }
        double fd = (double)(i0 / 400);
        double fh = (double)((i0 / 20) % 20);
        double fw = (double)(i0 % 20);
        const float* e = expd + (size_t)gid * 3;
        sum = fabs((double)e[0] - fd) + fabs((double)e[1] - fh) + fabs((double)e[2] - fw);
    }
    __shared__ double red[256];
    red[threadIdx.x] = sum;
    __syncthreads();
    for (int s = 128; s > 0; s >>= 1) {
        if (threadIdx.x < s) red[threadIdx.x] += red[threadIdx.x + s];
        __syncthreads();
    }
    if (threadIdx.x == 0) lpart[blockIdx.x] = red[0];
}

__global__ void k_final(const double* __restrict__ lpart, float* __restrict__ out) {
    int lane = threadIdx.x;                      // 64
    double v = (lane < 63) ? lpart[lane] : 0.0;
#pragma unroll
    for (int off = 32; off > 0; off >>= 1) v += __shfl_down(v, off);
    if (lane == 0) out[0] = (float)(v / 48000.0);
}

extern "C" void kernel_launch(void* const* d_in, const int* in_sizes, int n_in,
                              void* d_out, int out_size, void* d_ws, size_t ws_size,
                              hipStream_t stream) {
    const float* src  = (const float*)d_in[0];
    const float* tgt  = (const float*)d_in[1];
    const float* expd = (const float*)d_in[2];

    char* ws = (char*)d_ws;
    double* sfeat  = (double*)(ws);
    double* tfeat  = (double*)(ws + 2048000);
    double* t2     = (double*)(ws + 4096000);
    double* pscore = (double*)(ws + 4224000);
    int*    pidx   = (int*)(ws + 5248000);
    double* lpart  = (double*)(ws + 5760000);

    k_resize   <<<2000, 256, 0, stream>>>(src, tgt, sfeat, tfeat);
    k_t2       <<<63, 256, 0, stream>>>(tfeat, t2);
    k_argmin   <<<dim3(63, NCHUNK, BDIM), 256, 0, stream>>>(sfeat, tfeat, t2, pscore, pidx);
    k_mergeloss<<<63, 256, 0, stream>>>(pscore, pidx, expd, lpart);
    k_final    <<<1, 64, 0, stream>>>(lpart, (float*)d_out);
}

// Round 5
// 254.083 us; speedup vs baseline: 1.4630x; 1.4630x over previous
//
#include <hip/hip_runtime.h>
#include <stdint.h>
#include <math.h>

#define BDIM   2
#define CDIM   16
#define INS    64
#define OUTS   20
#define NPTS   8000          // 20^3
#define TOTN   (BDIM*NPTS)   // 16000

// Trilinear resize 64^3 -> 20^3 matching jax.image.resize(method='trilinear',
// antialias=True). All math in f64. (Unchanged — known exact.)
__global__ void k_resize(const float* __restrict__ src, const float* __restrict__ tgt,
                         double* __restrict__ sfeat, double* __restrict__ tfeat) {
    __shared__ double wts[OUTS][8];
    __shared__ int    st[OUTS];
    __shared__ int    cnt[OUTS];
    int tid = threadIdx.x;
    if (tid < OUTS) {
        double sample = (tid + 0.5) * 3.2 - 0.5;
        int lo = (int)ceil(sample - 3.2);
        int hi = (int)floor(sample + 3.2);
        if (lo < 0) lo = 0;
        if (hi > INS - 1) hi = INS - 1;
        int c = hi - lo + 1;           // <= 7
        double w[8];
        double sum = 0.0;
        for (int k = 0; k < 8; ++k) {
            double ww = 0.0;
            if (k < c) {
                double x = fabs(sample - (double)(lo + k)) * (1.0 / 3.2);
                ww = (x < 1.0) ? (1.0 - x) : 0.0;
            }
            w[k] = ww; sum += ww;
        }
        for (int k = 0; k < 8; ++k) wts[tid][k] = w[k] / sum;
        st[tid] = lo; cnt[tid] = c;
    }
    __syncthreads();

    int gid = blockIdx.x * blockDim.x + tid;     // [sel][b][c][od][oh][ow], 512000 total
    int ow = gid % OUTS; int r = gid / OUTS;
    int oh = r % OUTS;  r /= OUTS;
    int od = r % OUTS;  r /= OUTS;
    int c  = r % CDIM;  r /= CDIM;
    int b  = r % BDIM;  r /= BDIM;
    int sel = r;                                  // 0=src, 1=tgt

    const float* in   = sel ? tgt : src;
    double*      outf = sel ? tfeat : sfeat;

    const float* base = in + (((size_t)(b * CDIM + c)) << 18);   // * 64*64*64
    int sd = st[od], sh = st[oh], sw = st[ow];
    int cd = cnt[od], ch = cnt[oh], cw = cnt[ow];
    double wwv[8];
    for (int k = 0; k < 8; ++k) wwv[k] = wts[ow][k];

    double acc = 0.0;
    for (int id = 0; id < cd; ++id) {
        double wd = wts[od][id];
        const float* pd = base + ((size_t)(sd + id) << 12);
        for (int ih = 0; ih < ch; ++ih) {
            double wdh = wd * wts[oh][ih];
            const float* row = pd + ((sh + ih) << 6) + sw;
            for (int iw = 0; iw < cw; ++iw)
                acc = fma(wdh * wwv[iw], (double)row[iw], acc);
        }
    }
    int n = (od * OUTS + oh) * OUTS + ow;
    outf[((size_t)(b * NPTS + n)) * CDIM + c] = acc;
}

__global__ void k_t2(const double* __restrict__ tfeat, double* __restrict__ t2) {
    int i = blockIdx.x * blockDim.x + threadIdx.x;
    if (i >= TOTN) return;
    const double* p = tfeat + (size_t)i * CDIM;
    double a = 0, b = 0, c = 0, d = 0;
#pragma unroll
    for (int k = 0; k < 4; ++k) {
        a = fma(p[4*k+0], p[4*k+0], a);
        b = fma(p[4*k+1], p[4*k+1], b);
        c = fma(p[4*k+2], p[4*k+2], c);
        d = fma(p[4*k+3], p[4*k+3], d);
    }
    t2[i] = (a + b) + (c + d);
}

// Exact f64 argmin, T=4 n/thread (s-tile 128 VGPR, register-resident).
// The t-row address is wave-uniform (depends only on wp, i): wp is hoisted to
// an SGPR via readfirstlane so the t[16] / t2 loads compile to scalar (SMEM)
// loads through the K$, freeing the VMEM pipe; v_fma_f64 consumes the SGPR
// t-operands directly. 4 waves/block stride-interleave m (m = mbase + wp + 4i).
// Scores arithmetic-identical to previous rounds -> bitwise-exact argmin.
__global__ __launch_bounds__(256, 3) void k_argmin(const double* __restrict__ sfeat,
                                                   const double* __restrict__ tfeat,
                                                   const double* __restrict__ t2,
                                                   double* __restrict__ pscore,
                                                   int* __restrict__ pidx,
                                                   int mchunk, int nchunk) {
    int b     = blockIdx.z;
    int chunk = blockIdx.y;
    int nbase = blockIdx.x << 8;                 // *256
    int lane  = threadIdx.x & 63;
    int wp    = (int)__builtin_amdgcn_readfirstlane(threadIdx.x >> 6);  // SGPR 0..3

    double s[4][16];
#pragma unroll
    for (int j = 0; j < 4; ++j) {
        int n = nbase + lane + (j << 6);
        if (n > NPTS - 1) n = NPTS - 1;          // pad clamp (last n-tile)
        const double* sr = sfeat + ((size_t)(b * NPTS + n)) * CDIM;
#pragma unroll
        for (int k = 0; k < CDIM; ++k) s[j][k] = sr[k];
    }

    const double* tb  = tfeat + (size_t)b * NPTS * CDIM;
    const double* t2b = t2 + b * NPTS;

    int mbase = chunk * mchunk;
    int mlen  = NPTS - mbase; if (mlen > mchunk) mlen = mchunk;   // 668 or 652 tail
    int iters = mlen >> 2;

    double best[4] = {1e300, 1e300, 1e300, 1e300};
    int    bm[4]   = {0, 0, 0, 0};
    int mstart = mbase + wp;

#pragma unroll 2
    for (int i = 0; i < iters; ++i) {
        int m = mstart + (i << 2);               // SGPR arithmetic
        const double* tr = tb + (size_t)m * CDIM;
        double t[16];
#pragma unroll
        for (int k = 0; k < CDIM; ++k) t[k] = tr[k];   // uniform -> s_load
        double t2v = t2b[m];
#pragma unroll
        for (int j = 0; j < 4; ++j) {
            double d0 = 0, d1 = 0, d2 = 0, d3 = 0;
#pragma unroll
            for (int k = 0; k < 4; ++k) {
                d0 = fma(s[j][4*k+0], t[4*k+0], d0);
                d1 = fma(s[j][4*k+1], t[4*k+1], d1);
                d2 = fma(s[j][4*k+2], t[4*k+2], d2);
                d3 = fma(s[j][4*k+3], t[4*k+3], d3);
            }
            double dot   = (d0 + d1) + (d2 + d3);
            double score = fma(-2.0, dot, t2v);
            if (score < best[j]) { best[j] = score; bm[j] = m; }  // m ascending per thread
        }
    }

    // merge the 4 waves' candidates for the block's 256 n's (exact lexicographic)
    __shared__ double sc[1024];
    __shared__ int    sm[1024];
#pragma unroll
    for (int j = 0; j < 4; ++j) {
        sc[wp * 256 + lane * 4 + j] = best[j];
        sm[wp * 256 + lane * 4 + j] = bm[j];
    }
    __syncthreads();

    int tid = threadIdx.x;
    int e   = (tid & 63) * 4 + (tid >> 6);       // entry for n = nbase + tid
    double b0 = sc[e];
    int    i0 = sm[e];
#pragma unroll
    for (int p = 1; p < 4; ++p) {
        double bp = sc[p * 256 + e];
        int    ip = sm[p * 256 + e];
        if (bp < b0 || (bp == b0 && ip < i0)) { b0 = bp; i0 = ip; }
    }
    int n = nbase + tid;
    if (n < NPTS) {
        size_t o = ((size_t)(b * nchunk + chunk)) * NPTS + n;
        pscore[o] = b0;
        pidx[o]   = i0;
    }
}

// Merge chunks (ascending, strict < => earliest m wins ties) + partial loss.
__global__ void k_mergeloss(const double* __restrict__ pscore,
                            const int* __restrict__ pidx,
                            const float* __restrict__ expd,
                            double* __restrict__ lpart, int nchunk) {
    int gid = blockIdx.x * 256 + threadIdx.x;    // 63*256 = 16128 >= 16000
    double sum = 0.0;
    if (gid < TOTN) {
        int b  = gid / NPTS;
        int nn = gid % NPTS;
        size_t o = ((size_t)(b * nchunk)) * NPTS + nn;
        double b0 = pscore[o];
        int    i0 = pidx[o];
        for (int c = 1; c < nchunk; ++c) {
            double bp = pscore[o + (size_t)c * NPTS];
            int    ip = pidx[o + (size_t)c * NPTS];
            if (bp < b0) { b0 = bp; i0 = ip; }   // idx ascends with chunk
        }
        double fd = (double)(i0 / 400);
        double fh = (double)((i0 / 20) % 20);
        double fw = (double)(i0 % 20);
        const float* e = expd + (size_t)gid * 3;
        sum = fabs((double)e[0] - fd) + fabs((double)e[1] - fh) + fabs((double)e[2] - fw);
    }
    __shared__ double red[256];
    red[threadIdx.x] = sum;
    __syncthreads();
    for (int s = 128; s > 0; s >>= 1) {
        if (threadIdx.x < s) red[threadIdx.x] += red[threadIdx.x + s];
        __syncthreads();
    }
    if (threadIdx.x == 0) lpart[blockIdx.x] = red[0];
}

__global__ void k_final(const double* __restrict__ lpart, float* __restrict__ out) {
    int lane = threadIdx.x;                      // 64
    double v = (lane < 63) ? lpart[lane] : 0.0;
#pragma unroll
    for (int off = 32; off > 0; off >>= 1) v += __shfl_down(v, off);
    if (lane == 0) out[0] = (float)(v / 48000.0);
}

extern "C" void kernel_launch(void* const* d_in, const int* in_sizes, int n_in,
                              void* d_out, int out_size, void* d_ws, size_t ws_size,
                              hipStream_t stream) {
    const float* src  = (const float*)d_in[0];
    const float* tgt  = (const float*)d_in[1];
    const float* expd = (const float*)d_in[2];

    // pick chunking by available scratch: NCHUNK=12 (grid 768 = 3 blocks/CU)
    // needs ~6.54 MB; fall back to 8 (5.76 MB, known-fitting) otherwise.
    int nchunk = 12, mchunk = 668;
    {
        size_t need = 4224000ull + (size_t)BDIM * 12 * NPTS * 12 + 512;
        if (ws_size < need) { nchunk = 8; mchunk = 1000; }
    }

    char* ws = (char*)d_ws;
    double* sfeat  = (double*)(ws);                                  // 2,048,000
    double* tfeat  = (double*)(ws + 2048000);                        // 2,048,000
    double* t2     = (double*)(ws + 4096000);                        //   128,000
    double* pscore = (double*)(ws + 4224000);                        // B*nchunk*N*8
    size_t  psz    = (size_t)BDIM * nchunk * NPTS * 8;
    int*    pidx   = (int*)(ws + 4224000 + psz);                     // B*nchunk*N*4
    size_t  isz    = (size_t)BDIM * nchunk * NPTS * 4;
    double* lpart  = (double*)(ws + 4224000 + psz + isz);            // 63*8

    k_resize   <<<2000, 256, 0, stream>>>(src, tgt, sfeat, tfeat);
    k_t2       <<<63, 256, 0, stream>>>(tfeat, t2);
    k_argmin   <<<dim3(32, nchunk, BDIM), 256, 0, stream>>>(sfeat, tfeat, t2,
                                                            pscore, pidx, mchunk, nchunk);
    k_mergeloss<<<63, 256, 0, stream>>>(pscore, pidx, expd, lpart, nchunk);
    k_final    <<<1, 64, 0, stream>>>(lpart, (float*)d_out);
}